// Round 1
// baseline (518.639 us; speedup 1.0000x reference)
//
#include <hip/hip_runtime.h>
#include <math.h>

#define DIN 256
#define DHID 128
#define DOUTC 64

static __device__ __forceinline__ float wave_max(float v){
  #pragma unroll
  for (int o=1;o<64;o<<=1) v = fmaxf(v, __shfl_xor(v,o,64));
  return v;
}
static __device__ __forceinline__ float wave_sum(float v){
  #pragma unroll
  for (int o=1;o<64;o<<=1) v += __shfl_xor(v,o,64);
  return v;
}

// ---------------- CSR build ----------------
__global__ void hist_kernel(const int* __restrict__ dst, int* __restrict__ counts, int E){
  int i = blockIdx.x*256 + threadIdx.x;
  if (i < E) atomicAdd(&counts[dst[i]], 1);
}

__global__ void scan1_kernel(const int* __restrict__ counts, int* __restrict__ tmp,
                             int* __restrict__ bsum, int N){
  __shared__ int b[256];
  int t = threadIdx.x;
  int i = blockIdx.x*256 + t;
  int v = (i<N)? counts[i] : 0;
  b[t] = v; __syncthreads();
  #pragma unroll
  for (int o=1;o<256;o<<=1){
    int x = (t>=o)? b[t-o] : 0;
    __syncthreads();
    b[t] += x;
    __syncthreads();
  }
  if (i<N) tmp[i] = b[t]-v;          // exclusive within block
  if (t==255) bsum[blockIdx.x] = b[255];
}

__global__ void scan2_kernel(int* __restrict__ bsum, int nb){
  __shared__ int b[256];
  int t = threadIdx.x;
  int v = (t<nb)? bsum[t] : 0;
  b[t]=v; __syncthreads();
  #pragma unroll
  for (int o=1;o<256;o<<=1){
    int x = (t>=o)? b[t-o] : 0;
    __syncthreads();
    b[t] += x;
    __syncthreads();
  }
  if (t<nb) bsum[t] = b[t]-v;        // exclusive block offsets
}

__global__ void scan3_kernel(const int* __restrict__ tmp, const int* __restrict__ bsum,
                             int* __restrict__ offsets, int* __restrict__ cursor, int N, int E){
  int i = blockIdx.x*256 + threadIdx.x;
  if (i<N){ int o = tmp[i] + bsum[blockIdx.x]; offsets[i]=o; cursor[i]=o; }
  if (i==0) offsets[N]=E;
}

__global__ void scatter_kernel(const int* __restrict__ src, const int* __restrict__ dst,
                               int* __restrict__ cursor, int* __restrict__ srcs, int E){
  int i = blockIdx.x*256 + threadIdx.x;
  if (i < E){
    int pos = atomicAdd(&cursor[dst[i]], 1);
    srcs[pos] = src[i];
  }
}

// ---------------- GEMM: F[N x BN] = A[N x K] @ W[K x BN] ----------------
template<int BN>
__global__ __launch_bounds__(256) void gemm_kernel(const float* __restrict__ A,
    const float* __restrict__ W, float* __restrict__ F, int nrows, int K)
{
  constexpr int TX = BN/4;        // threads along cols (each does 4 cols)
  constexpr int TY = 256/TX;      // row groups (each does 8 rows)
  constexpr int BM = TY*8;        // rows per block
  constexpr int LDA = BM + 8;     // padded (16B-aligned, conflict-light)
  __shared__ float As[32][LDA];   // transposed A tile: As[k][r]
  __shared__ float Bs[32][BN];

  const int tid = threadIdx.x;
  const int tx = tid % TX, ty = tid / TX;
  const int row0 = blockIdx.x * BM;

  float acc[8][4];
  #pragma unroll
  for (int i=0;i<8;i++)
    #pragma unroll
    for (int j=0;j<4;j++) acc[i][j]=0.f;

  for (int kt=0; kt<K; kt+=32){
    #pragma unroll
    for (int it=0; it< (BM*8)/256; ++it){
      int idx = it*256 + tid;
      int r = idx >> 3;
      int kq = (idx & 7) * 4;
      int grow = row0 + r;
      float4 v = make_float4(0.f,0.f,0.f,0.f);
      if (grow < nrows) v = *(const float4*)&A[(size_t)grow*K + kt + kq];
      As[kq+0][r]=v.x; As[kq+1][r]=v.y; As[kq+2][r]=v.z; As[kq+3][r]=v.w;
    }
    #pragma unroll
    for (int it=0; it< (32*BN/4)/256; ++it){
      int idx = it*256 + tid;
      int c = (idx % (BN/4))*4;
      int kr = idx / (BN/4);
      *(float4*)&Bs[kr][c] = *(const float4*)&W[(size_t)(kt+kr)*BN + c];
    }
    __syncthreads();
    #pragma unroll
    for (int k=0;k<32;k++){
      float4 b = *(const float4*)&Bs[k][tx*4];
      float4 a0 = *(const float4*)&As[k][ty*8];
      float4 a1 = *(const float4*)&As[k][ty*8+4];
      float av[8] = {a0.x,a0.y,a0.z,a0.w,a1.x,a1.y,a1.z,a1.w};
      float bv[4] = {b.x,b.y,b.z,b.w};
      #pragma unroll
      for (int i=0;i<8;i++)
        #pragma unroll
        for (int j=0;j<4;j++)
          acc[i][j] = fmaf(av[i], bv[j], acc[i][j]);
    }
    __syncthreads();
  }
  #pragma unroll
  for (int i=0;i<8;i++){
    int grow = row0 + ty*8 + i;
    if (grow < nrows)
      *(float4*)&F[(size_t)grow*BN + tx*4] =
        make_float4(acc[i][0],acc[i][1],acc[i][2],acc[i][3]);
  }
}

// ---------------- el/er: dot of each f row with al/ar ----------------
template<int D>
__global__ __launch_bounds__(256) void elr_kernel(const float* __restrict__ F,
   const float* __restrict__ al, const float* __restrict__ ar,
   float* __restrict__ el, float* __restrict__ er, int N)
{
  int v = blockIdx.x*4 + (threadIdx.x>>6);
  int lane = threadIdx.x & 63;
  if (v>=N) return;
  float sl=0.f, sr=0.f;
  #pragma unroll
  for (int c=lane;c<D;c+=64){
    float f = F[(size_t)v*D+c];
    sl = fmaf(f, al[c], sl);
    sr = fmaf(f, ar[c], sr);
  }
  sl = wave_sum(sl); sr = wave_sum(sr);
  if (lane==0){ el[v]=sl; er[v]=sr; }
}

// ---------------- per-node edge softmax + aggregate ----------------
template<int D, bool RELU, bool LOGSM>
__global__ __launch_bounds__(256) void agg_kernel(const float* __restrict__ F,
    const float* __restrict__ el, const float* __restrict__ er,
    const int* __restrict__ offsets, const int* __restrict__ srcs,
    float* __restrict__ out, int N)
{
  int v = blockIdx.x*4 + (threadIdx.x>>6);
  int lane = threadIdx.x & 63;
  if (v>=N) return;
  int o0 = offsets[v], o1 = offsets[v+1];
  float erv = er[v];

  float m = -INFINITY;
  for (int j=o0+lane; j<o1; j+=64){
    float e = el[srcs[j]] + erv;
    e = (e>0.f)? e : 0.2f*e;
    m = fmaxf(m, e);
  }
  m = wave_max(m);

  float z = 0.f;
  for (int j=o0+lane; j<o1; j+=64){
    float e = el[srcs[j]] + erv;
    e = (e>0.f)? e : 0.2f*e;
    z += expf(e-m);
  }
  z = wave_sum(z);
  float zi = 1.f / fmaxf(z, 1e-9f);

  float acc0=0.f, acc1=0.f;
  for (int j=o0; j<o1; ++j){
    int s = srcs[j];
    float e = el[s] + erv;
    e = (e>0.f)? e : 0.2f*e;
    float w = expf(e-m)*zi;
    acc0 = fmaf(w, F[(size_t)s*D + lane], acc0);
    if (D==128) acc1 = fmaf(w, F[(size_t)s*D + 64 + lane], acc1);
  }
  if (RELU){ acc0 = fmaxf(acc0,0.f); if (D==128) acc1 = fmaxf(acc1,0.f); }

  if (LOGSM){
    float M = wave_max(acc0);
    float s = wave_sum(expf(acc0-M));
    out[(size_t)v*D + lane] = acc0 - M - logf(s);
  } else {
    out[(size_t)v*D + lane] = acc0;
    if (D==128) out[(size_t)v*D + 64 + lane] = acc1;
  }
}

// ---------------- launch ----------------
extern "C" void kernel_launch(void* const* d_in, const int* in_sizes, int n_in,
                              void* d_out, int out_size, void* d_ws, size_t ws_size,
                              hipStream_t stream) {
  const float* h   = (const float*)d_in[0];
  const int*   src = (const int*)d_in[1];
  const int*   dst = (const int*)d_in[2];
  const float* W1  = (const float*)d_in[3];
  const float* al1 = (const float*)d_in[4];
  const float* ar1 = (const float*)d_in[5];
  const float* W2  = (const float*)d_in[6];
  const float* al2 = (const float*)d_in[7];
  const float* ar2 = (const float*)d_in[8];
  const float* W3  = (const float*)d_in[9];
  const float* al3 = (const float*)d_in[10];
  const float* ar3 = (const float*)d_in[11];

  const int N = in_sizes[0] / DIN;
  const int E = in_sizes[1];

  auto alignup = [](size_t x){ return (x + 255) & ~(size_t)255; };
  char* p = (char*)d_ws;
  int* counts  = (int*)p; p += alignup((size_t)N*4);
  int* offsets = (int*)p; p += alignup(((size_t)N+1)*4);
  int* cursor  = (int*)p; p += alignup((size_t)N*4);
  int* tmp     = (int*)p; p += alignup((size_t)N*4);
  int* bsum    = (int*)p; p += alignup(256*4);
  int* srcs    = (int*)p; p += alignup((size_t)E*4);
  float* F     = (float*)p; p += alignup((size_t)N*DHID*4);
  float* X     = (float*)p; p += alignup((size_t)N*DHID*4);
  float* el    = (float*)p; p += alignup((size_t)N*4);
  float* er    = (float*)p; p += alignup((size_t)N*4);

  const int nbN  = (N+255)/256;
  const int nbE  = (E+255)/256;
  const int nbW4 = (N+3)/4;      // wave-per-node kernels, 4 nodes/block

  hipMemsetAsync(counts, 0, (size_t)N*4, stream);
  hist_kernel<<<nbE,256,0,stream>>>(dst, counts, E);
  scan1_kernel<<<nbN,256,0,stream>>>(counts, tmp, bsum, N);
  scan2_kernel<<<1,256,0,stream>>>(bsum, nbN);
  scan3_kernel<<<nbN,256,0,stream>>>(tmp, bsum, offsets, cursor, N, E);
  scatter_kernel<<<nbE,256,0,stream>>>(src, dst, cursor, srcs, E);

  // Layer 1: [N,256]@[256,128]
  gemm_kernel<128><<<(N+63)/64,256,0,stream>>>(h, W1, F, N, DIN);
  elr_kernel<128><<<nbW4,256,0,stream>>>(F, al1, ar1, el, er, N);
  agg_kernel<128,true,false><<<nbW4,256,0,stream>>>(F, el, er, offsets, srcs, X, N);

  // Layer 2: [N,128]@[128,128]
  gemm_kernel<128><<<(N+63)/64,256,0,stream>>>(X, W2, F, N, DHID);
  elr_kernel<128><<<nbW4,256,0,stream>>>(F, al2, ar2, el, er, N);
  agg_kernel<128,true,false><<<nbW4,256,0,stream>>>(F, el, er, offsets, srcs, X, N);

  // Layer 3: [N,128]@[128,64] + log_softmax
  gemm_kernel<64><<<(N+127)/128,256,0,stream>>>(X, W3, F, N, DHID);
  elr_kernel<64><<<nbW4,256,0,stream>>>(F, al3, ar3, el, er, N);
  agg_kernel<64,false,true><<<nbW4,256,0,stream>>>(F, el, er, offsets, srcs, (float*)d_out, N);
}

// Round 2
// 374.339 us; speedup vs baseline: 1.3855x; 1.3855x over previous
//
#include <hip/hip_runtime.h>
#include <math.h>

#define DIN 256
#define DHID 128
#define DOUTC 64

static __device__ __forceinline__ float wave_max(float v){
  #pragma unroll
  for (int o=1;o<64;o<<=1) v = fmaxf(v, __shfl_xor(v,o,64));
  return v;
}
static __device__ __forceinline__ float wave_sum(float v){
  #pragma unroll
  for (int o=1;o<64;o<<=1) v += __shfl_xor(v,o,64);
  return v;
}

// ---------------- CSR build ----------------
__global__ void hist_kernel(const int* __restrict__ dst, int* __restrict__ counts, int E){
  int i = blockIdx.x*256 + threadIdx.x;
  if (i < E) atomicAdd(&counts[dst[i]], 1);
}

__global__ void scan1_kernel(const int* __restrict__ counts, int* __restrict__ tmp,
                             int* __restrict__ bsum, int N){
  __shared__ int b[256];
  int t = threadIdx.x;
  int i = blockIdx.x*256 + t;
  int v = (i<N)? counts[i] : 0;
  b[t] = v; __syncthreads();
  #pragma unroll
  for (int o=1;o<256;o<<=1){
    int x = (t>=o)? b[t-o] : 0;
    __syncthreads();
    b[t] += x;
    __syncthreads();
  }
  if (i<N) tmp[i] = b[t]-v;          // exclusive within block
  if (t==255) bsum[blockIdx.x] = b[255];
}

__global__ void scan2_kernel(int* __restrict__ bsum, int nb){
  __shared__ int b[256];
  int t = threadIdx.x;
  int v = (t<nb)? bsum[t] : 0;
  b[t]=v; __syncthreads();
  #pragma unroll
  for (int o=1;o<256;o<<=1){
    int x = (t>=o)? b[t-o] : 0;
    __syncthreads();
    b[t] += x;
    __syncthreads();
  }
  if (t<nb) bsum[t] = b[t]-v;        // exclusive block offsets
}

__global__ void scan3_kernel(const int* __restrict__ tmp, const int* __restrict__ bsum,
                             int* __restrict__ offsets, int* __restrict__ cursor, int N, int E){
  int i = blockIdx.x*256 + threadIdx.x;
  if (i<N){ int o = tmp[i] + bsum[blockIdx.x]; offsets[i]=o; cursor[i]=o; }
  if (i==0) offsets[N]=E;
}

__global__ void scatter_kernel(const int* __restrict__ src, const int* __restrict__ dst,
                               int* __restrict__ cursor, int* __restrict__ srcs, int E){
  int i = blockIdx.x*256 + threadIdx.x;
  if (i < E){
    int pos = atomicAdd(&cursor[dst[i]], 1);
    srcs[pos] = src[i];
  }
}

// ---------------- GEMM: F[N x BN] = A[N x K] @ W[K x BN] ----------------
template<int BN>
__global__ __launch_bounds__(256) void gemm_kernel(const float* __restrict__ A,
    const float* __restrict__ W, float* __restrict__ F, int nrows, int K)
{
  constexpr int TX = BN/4;        // threads along cols (each does 4 cols)
  constexpr int TY = 256/TX;      // row groups (each does 8 rows)
  constexpr int BM = TY*8;        // rows per block
  constexpr int LDA = BM + 8;     // padded (16B-aligned, conflict-light)
  __shared__ float As[32][LDA];   // transposed A tile: As[k][r]
  __shared__ float Bs[32][BN];

  const int tid = threadIdx.x;
  const int tx = tid % TX, ty = tid / TX;
  const int row0 = blockIdx.x * BM;

  float acc[8][4];
  #pragma unroll
  for (int i=0;i<8;i++)
    #pragma unroll
    for (int j=0;j<4;j++) acc[i][j]=0.f;

  for (int kt=0; kt<K; kt+=32){
    #pragma unroll
    for (int it=0; it< (BM*8)/256; ++it){
      int idx = it*256 + tid;
      int r = idx >> 3;
      int kq = (idx & 7) * 4;
      int grow = row0 + r;
      float4 v = make_float4(0.f,0.f,0.f,0.f);
      if (grow < nrows) v = *(const float4*)&A[(size_t)grow*K + kt + kq];
      As[kq+0][r]=v.x; As[kq+1][r]=v.y; As[kq+2][r]=v.z; As[kq+3][r]=v.w;
    }
    #pragma unroll
    for (int it=0; it< (32*BN/4)/256; ++it){
      int idx = it*256 + tid;
      int c = (idx % (BN/4))*4;
      int kr = idx / (BN/4);
      *(float4*)&Bs[kr][c] = *(const float4*)&W[(size_t)(kt+kr)*BN + c];
    }
    __syncthreads();
    #pragma unroll
    for (int k=0;k<32;k++){
      float4 b = *(const float4*)&Bs[k][tx*4];
      float4 a0 = *(const float4*)&As[k][ty*8];
      float4 a1 = *(const float4*)&As[k][ty*8+4];
      float av[8] = {a0.x,a0.y,a0.z,a0.w,a1.x,a1.y,a1.z,a1.w};
      float bv[4] = {b.x,b.y,b.z,b.w};
      #pragma unroll
      for (int i=0;i<8;i++)
        #pragma unroll
        for (int j=0;j<4;j++)
          acc[i][j] = fmaf(av[i], bv[j], acc[i][j]);
    }
    __syncthreads();
  }
  #pragma unroll
  for (int i=0;i<8;i++){
    int grow = row0 + ty*8 + i;
    if (grow < nrows)
      *(float4*)&F[(size_t)grow*BN + tx*4] =
        make_float4(acc[i][0],acc[i][1],acc[i][2],acc[i][3]);
  }
}

// ---------------- el/er: dot of each f row with al/ar ----------------
template<int D>
__global__ __launch_bounds__(256) void elr_kernel(const float* __restrict__ F,
   const float* __restrict__ al, const float* __restrict__ ar,
   float* __restrict__ el, float* __restrict__ er, int N)
{
  int v = blockIdx.x*4 + (threadIdx.x>>6);
  int lane = threadIdx.x & 63;
  if (v>=N) return;
  float sl=0.f, sr=0.f;
  #pragma unroll
  for (int c=lane;c<D;c+=64){
    float f = F[(size_t)v*D+c];
    sl = fmaf(f, al[c], sl);
    sr = fmaf(f, ar[c], sr);
  }
  sl = wave_sum(sl); sr = wave_sum(sr);
  if (lane==0){ el[v]=sl; er[v]=sr; }
}

// ---------------- per-node online edge softmax + aggregate (single pass) ----------------
// One wave per node, 4 nodes/block. Chunk edges by 64:
//   lane-parallel: gather el, leaky_relu, online-max rescale, exp -> (w,src) to LDS
//   wave-serial:   broadcast (w,src) from LDS, gather F row (float2/lane), fmaf, x4 unroll
template<int D, bool RELU, bool LOGSM>
__global__ __launch_bounds__(256) void agg2_kernel(const float* __restrict__ F,
    const float* __restrict__ el, const float* __restrict__ er,
    const int* __restrict__ offsets, const int* __restrict__ srcs,
    float* __restrict__ out, int N)
{
  __shared__ float2 ws[4][64];
  const int wv = threadIdx.x >> 6;
  const int lane = threadIdx.x & 63;
  const int v = blockIdx.x*4 + wv;
  if (v >= N) return;
  const int o0 = offsets[v], o1 = offsets[v+1];
  const float erv = er[v];

  float m = -INFINITY, z = 0.f;
  float acc0 = 0.f, acc1 = 0.f;

  for (int c0 = o0; c0 < o1; c0 += 64){
    const int j = c0 + lane;
    int s = 0; float e = -INFINITY;
    if (j < o1){
      s = srcs[j];
      float t = el[s] + erv;
      e = (t > 0.f) ? t : 0.2f*t;
    }
    const float nm = fmaxf(m, wave_max(e));
    const float scale = __expf(m - nm);   // first chunk: exp(-inf)=0
    const float wgt = __expf(e - nm);     // invalid lanes: exp(-inf)=0
    z = z*scale + wave_sum(wgt);
    acc0 *= scale; if (D==128) acc1 *= scale;
    m = nm;
    ws[wv][lane] = make_float2(wgt, __int_as_float(s));
    __builtin_amdgcn_wave_barrier();

    const int cnt = min(64, o1 - c0);
    int t = 0;
    if (D == 128){
      const float* Fb = F + lane*2;
      for (; t+4 <= cnt; t += 4){
        float2 p0 = ws[wv][t+0], p1 = ws[wv][t+1];
        float2 p2 = ws[wv][t+2], p3 = ws[wv][t+3];
        float2 f0 = *(const float2*)(Fb + __float_as_int(p0.y)*128);
        float2 f1 = *(const float2*)(Fb + __float_as_int(p1.y)*128);
        float2 f2 = *(const float2*)(Fb + __float_as_int(p2.y)*128);
        float2 f3 = *(const float2*)(Fb + __float_as_int(p3.y)*128);
        acc0 = fmaf(p0.x, f0.x, acc0); acc1 = fmaf(p0.x, f0.y, acc1);
        acc0 = fmaf(p1.x, f1.x, acc0); acc1 = fmaf(p1.x, f1.y, acc1);
        acc0 = fmaf(p2.x, f2.x, acc0); acc1 = fmaf(p2.x, f2.y, acc1);
        acc0 = fmaf(p3.x, f3.x, acc0); acc1 = fmaf(p3.x, f3.y, acc1);
      }
      for (; t < cnt; ++t){
        float2 p = ws[wv][t];
        float2 f = *(const float2*)(Fb + __float_as_int(p.y)*128);
        acc0 = fmaf(p.x, f.x, acc0); acc1 = fmaf(p.x, f.y, acc1);
      }
    } else {
      const float* Fb = F + lane;
      for (; t+4 <= cnt; t += 4){
        float2 p0 = ws[wv][t+0], p1 = ws[wv][t+1];
        float2 p2 = ws[wv][t+2], p3 = ws[wv][t+3];
        float f0 = Fb[__float_as_int(p0.y)*64];
        float f1 = Fb[__float_as_int(p1.y)*64];
        float f2 = Fb[__float_as_int(p2.y)*64];
        float f3 = Fb[__float_as_int(p3.y)*64];
        acc0 = fmaf(p0.x, f0, acc0);
        acc0 = fmaf(p1.x, f1, acc0);
        acc0 = fmaf(p2.x, f2, acc0);
        acc0 = fmaf(p3.x, f3, acc0);
      }
      for (; t < cnt; ++t){
        float2 p = ws[wv][t];
        acc0 = fmaf(p.x, Fb[__float_as_int(p.y)*64], acc0);
      }
    }
    __builtin_amdgcn_wave_barrier();
  }

  const float zi = 1.f / fmaxf(z, 1e-9f);
  if (LOGSM){
    float y = acc0 * zi;
    float M = wave_max(y);
    float sum = wave_sum(__expf(y - M));
    out[(size_t)v*D + lane] = y - M - logf(sum);
  } else if (D == 128){
    float2 o;
    o.x = acc0*zi; o.y = acc1*zi;
    if (RELU){ o.x = fmaxf(o.x,0.f); o.y = fmaxf(o.y,0.f); }
    *(float2*)&out[(size_t)v*128 + lane*2] = o;
  } else {
    float o = acc0*zi;
    if (RELU) o = fmaxf(o,0.f);
    out[(size_t)v*64 + lane] = o;
  }
}

// ---------------- launch ----------------
extern "C" void kernel_launch(void* const* d_in, const int* in_sizes, int n_in,
                              void* d_out, int out_size, void* d_ws, size_t ws_size,
                              hipStream_t stream) {
  const float* h   = (const float*)d_in[0];
  const int*   src = (const int*)d_in[1];
  const int*   dst = (const int*)d_in[2];
  const float* W1  = (const float*)d_in[3];
  const float* al1 = (const float*)d_in[4];
  const float* ar1 = (const float*)d_in[5];
  const float* W2  = (const float*)d_in[6];
  const float* al2 = (const float*)d_in[7];
  const float* ar2 = (const float*)d_in[8];
  const float* W3  = (const float*)d_in[9];
  const float* al3 = (const float*)d_in[10];
  const float* ar3 = (const float*)d_in[11];

  const int N = in_sizes[0] / DIN;
  const int E = in_sizes[1];

  auto alignup = [](size_t x){ return (x + 255) & ~(size_t)255; };
  char* p = (char*)d_ws;
  int* counts  = (int*)p; p += alignup((size_t)N*4);
  int* offsets = (int*)p; p += alignup(((size_t)N+1)*4);
  int* cursor  = (int*)p; p += alignup((size_t)N*4);
  int* tmp     = (int*)p; p += alignup((size_t)N*4);
  int* bsum    = (int*)p; p += alignup(256*4);
  int* srcs    = (int*)p; p += alignup((size_t)E*4);
  float* F     = (float*)p; p += alignup((size_t)N*DHID*4);
  float* X     = (float*)p; p += alignup((size_t)N*DHID*4);
  float* el    = (float*)p; p += alignup((size_t)N*4);
  float* er    = (float*)p; p += alignup((size_t)N*4);

  const int nbN  = (N+255)/256;
  const int nbE  = (E+255)/256;
  const int nbW4 = (N+3)/4;      // wave-per-node kernels, 4 nodes/block

  hipMemsetAsync(counts, 0, (size_t)N*4, stream);
  hist_kernel<<<nbE,256,0,stream>>>(dst, counts, E);
  scan1_kernel<<<nbN,256,0,stream>>>(counts, tmp, bsum, N);
  scan2_kernel<<<1,256,0,stream>>>(bsum, nbN);
  scan3_kernel<<<nbN,256,0,stream>>>(tmp, bsum, offsets, cursor, N, E);
  scatter_kernel<<<nbE,256,0,stream>>>(src, dst, cursor, srcs, E);

  // Layer 1: [N,256]@[256,128]
  gemm_kernel<128><<<(N+63)/64,256,0,stream>>>(h, W1, F, N, DIN);
  elr_kernel<128><<<nbW4,256,0,stream>>>(F, al1, ar1, el, er, N);
  agg2_kernel<128,true,false><<<nbW4,256,0,stream>>>(F, el, er, offsets, srcs, X, N);

  // Layer 2: [N,128]@[128,128]
  gemm_kernel<128><<<(N+63)/64,256,0,stream>>>(X, W2, F, N, DHID);
  elr_kernel<128><<<nbW4,256,0,stream>>>(F, al2, ar2, el, er, N);
  agg2_kernel<128,true,false><<<nbW4,256,0,stream>>>(F, el, er, offsets, srcs, X, N);

  // Layer 3: [N,128]@[128,64] + log_softmax
  gemm_kernel<64><<<(N+127)/128,256,0,stream>>>(X, W3, F, N, DHID);
  elr_kernel<64><<<nbW4,256,0,stream>>>(F, al3, ar3, el, er, N);
  agg2_kernel<64,false,true><<<nbW4,256,0,stream>>>(F, el, er, offsets, srcs, (float*)d_out, N);
}

// Round 3
// 322.601 us; speedup vs baseline: 1.6077x; 1.1604x over previous
//
#include <hip/hip_runtime.h>
#include <math.h>

#define DIN 256
#define DHID 128
#define DOUTC 64

typedef __attribute__((ext_vector_type(8))) short short8;
typedef __attribute__((ext_vector_type(4))) float f32x4;

static __device__ __forceinline__ float wave_max(float v){
  #pragma unroll
  for (int o=1;o<64;o<<=1) v = fmaxf(v, __shfl_xor(v,o,64));
  return v;
}
static __device__ __forceinline__ float wave_sum(float v){
  #pragma unroll
  for (int o=1;o<64;o<<=1) v += __shfl_xor(v,o,64);
  return v;
}

static __device__ __forceinline__ unsigned short bf16_rne(float x){
  unsigned int u = __float_as_uint(x);
  return (unsigned short)((u + 0x7FFFu + ((u>>16)&1u)) >> 16);
}
static __device__ __forceinline__ float bf16_to_f32(unsigned short h){
  return __uint_as_float(((unsigned int)h)<<16);
}

// ---------------- CSR build ----------------
__global__ void hist_kernel(const int* __restrict__ dst, int* __restrict__ counts, int E){
  int i = blockIdx.x*256 + threadIdx.x;
  if (i < E) atomicAdd(&counts[dst[i]], 1);
}

__global__ void scan1_kernel(const int* __restrict__ counts, int* __restrict__ tmp,
                             int* __restrict__ bsum, int N){
  __shared__ int b[256];
  int t = threadIdx.x;
  int i = blockIdx.x*256 + t;
  int v = (i<N)? counts[i] : 0;
  b[t] = v; __syncthreads();
  #pragma unroll
  for (int o=1;o<256;o<<=1){
    int x = (t>=o)? b[t-o] : 0;
    __syncthreads();
    b[t] += x;
    __syncthreads();
  }
  if (i<N) tmp[i] = b[t]-v;
  if (t==255) bsum[blockIdx.x] = b[255];
}

__global__ void scan2_kernel(int* __restrict__ bsum, int nb){
  __shared__ int b[256];
  int t = threadIdx.x;
  int v = (t<nb)? bsum[t] : 0;
  b[t]=v; __syncthreads();
  #pragma unroll
  for (int o=1;o<256;o<<=1){
    int x = (t>=o)? b[t-o] : 0;
    __syncthreads();
    b[t] += x;
    __syncthreads();
  }
  if (t<nb) bsum[t] = b[t]-v;
}

__global__ void scan3_kernel(const int* __restrict__ tmp, const int* __restrict__ bsum,
                             int* __restrict__ offsets, int* __restrict__ cursor, int N, int E){
  int i = blockIdx.x*256 + threadIdx.x;
  if (i<N){ int o = tmp[i] + bsum[blockIdx.x]; offsets[i]=o; cursor[i]=o; }
  if (i==0) offsets[N]=E;
}

__global__ void scatter_kernel(const int* __restrict__ src, const int* __restrict__ dst,
                               int* __restrict__ cursor, int* __restrict__ srcs, int E){
  int i = blockIdx.x*256 + threadIdx.x;
  if (i < E){
    int pos = atomicAdd(&cursor[dst[i]], 1);
    srcs[pos] = src[i];
  }
}

// ---- pack W into MFMA B-fragment order, bf16 hi/lo interleaved (16+16 shorts/lane) ----
// Fragment t = kt*CT+ct, lane l: B[k = kt*32 + 8*(l>>4)+j][col = ct*16 + (l&15)], j=0..7
template<int K, int NC>
__global__ void pack_kernel(const float* __restrict__ W, unsigned short* __restrict__ Wp){
  constexpr int CT = NC/16, KT = K/32;
  int idx = blockIdx.x*256 + threadIdx.x;
  if (idx >= KT*CT*64) return;
  int l = idx & 63, t = idx >> 6;
  int ct = t % CT, kt = t / CT;
  int col = ct*16 + (l & 15);
  int k0 = kt*32 + (l >> 4)*8;
  unsigned short* dstp = Wp + (size_t)idx*16;
  #pragma unroll
  for (int j=0;j<8;j++){
    float x = W[(size_t)(k0+j)*NC + col];
    unsigned short h = bf16_rne(x);
    dstp[j] = h;
    dstp[8+j] = bf16_rne(x - bf16_to_f32(h));
  }
}

// ---- MFMA GEMM (bf16x3, fp32-class precision) + fused el/er ----
// 4 waves/block, 16 rows/wave, no LDS, no barriers.
template<int K, int NC>
__global__ __launch_bounds__(256) void gemm_mfma(const float* __restrict__ A,
    const unsigned short* __restrict__ Wp,
    const float* __restrict__ al, const float* __restrict__ ar,
    float* __restrict__ F, float* __restrict__ el, float* __restrict__ er, int nrows)
{
  constexpr int CT = NC/16, KT = K/32;
  const int lane = threadIdx.x & 63;
  const int wid  = threadIdx.x >> 6;
  const int row0 = blockIdx.x*64 + wid*16;
  const int c = lane & 15, g = lane >> 4;
  const int arow = row0 + c;            // A-fragment: row = lane&15
  const bool aok = arow < nrows;

  f32x4 acc[CT];
  #pragma unroll
  for (int i=0;i<CT;i++) acc[i] = (f32x4)0.f;

  #pragma unroll
  for (int kt=0; kt<KT; ++kt){
    const int k0 = kt*32 + g*8;         // k-group = lane>>4
    float xs[8];
    if (aok){
      float4 v0 = *(const float4*)&A[(size_t)arow*K + k0];
      float4 v1 = *(const float4*)&A[(size_t)arow*K + k0 + 4];
      xs[0]=v0.x; xs[1]=v0.y; xs[2]=v0.z; xs[3]=v0.w;
      xs[4]=v1.x; xs[5]=v1.y; xs[6]=v1.z; xs[7]=v1.w;
    } else {
      #pragma unroll
      for (int j=0;j<8;j++) xs[j]=0.f;
    }
    short8 ahi, alo;
    #pragma unroll
    for (int j=0;j<8;j++){
      unsigned short h = bf16_rne(xs[j]);
      ahi[j] = (short)h;
      alo[j] = (short)bf16_rne(xs[j] - bf16_to_f32(h));
    }
    #pragma unroll
    for (int ct=0; ct<CT; ++ct){
      const size_t base = ((size_t)((kt*CT+ct)*64 + lane))*16;
      short8 bhi = *(const short8*)&Wp[base];
      short8 blo = *(const short8*)&Wp[base+8];
      acc[ct] = __builtin_amdgcn_mfma_f32_16x16x32_bf16(ahi, bhi, acc[ct], 0,0,0);
      acc[ct] = __builtin_amdgcn_mfma_f32_16x16x32_bf16(alo, bhi, acc[ct], 0,0,0);
      acc[ct] = __builtin_amdgcn_mfma_f32_16x16x32_bf16(ahi, blo, acc[ct], 0,0,0);
    }
  }

  // epilogue: C/D layout row=(lane>>4)*4+j, col=lane&15. Store F + fused el/er.
  float alv[CT], arv[CT];
  #pragma unroll
  for (int ct=0;ct<CT;ct++){ alv[ct]=al[ct*16+c]; arv[ct]=ar[ct*16+c]; }
  #pragma unroll
  for (int j=0;j<4;j++){
    const int row = row0 + g*4 + j;
    const bool ok = row < nrows;
    float sl=0.f, sr=0.f;
    #pragma unroll
    for (int ct=0;ct<CT;ct++){
      float f = acc[ct][j];
      sl = fmaf(f, alv[ct], sl);
      sr = fmaf(f, arv[ct], sr);
      if (ok) F[(size_t)row*NC + ct*16 + c] = f;
    }
    #pragma unroll
    for (int o=1;o<16;o<<=1){ sl += __shfl_xor(sl,o,64); sr += __shfl_xor(sr,o,64); }
    if (ok && c==0){ el[row]=sl; er[row]=sr; }
  }
}

// ---------------- per-node online edge softmax + aggregate (single pass) ----------------
template<int D, bool RELU, bool LOGSM>
__global__ __launch_bounds__(256) void agg2_kernel(const float* __restrict__ F,
    const float* __restrict__ el, const float* __restrict__ er,
    const int* __restrict__ offsets, const int* __restrict__ srcs,
    float* __restrict__ out, int N)
{
  __shared__ float2 ws[4][64];
  const int wv = threadIdx.x >> 6;
  const int lane = threadIdx.x & 63;
  const int v = blockIdx.x*4 + wv;
  if (v >= N) return;
  const int o0 = offsets[v], o1 = offsets[v+1];
  const float erv = er[v];

  float m = -INFINITY, z = 0.f;
  float acc0 = 0.f, acc1 = 0.f;

  for (int c0 = o0; c0 < o1; c0 += 64){
    const int j = c0 + lane;
    int s = 0; float e = -INFINITY;
    if (j < o1){
      s = srcs[j];
      float t = el[s] + erv;
      e = (t > 0.f) ? t : 0.2f*t;
    }
    const float nm = fmaxf(m, wave_max(e));
    const float scale = __expf(m - nm);
    const float wgt = __expf(e - nm);
    z = z*scale + wave_sum(wgt);
    acc0 *= scale; if (D==128) acc1 *= scale;
    m = nm;
    ws[wv][lane] = make_float2(wgt, __int_as_float(s));
    __builtin_amdgcn_wave_barrier();

    const int cnt = min(64, o1 - c0);
    int t = 0;
    if (D == 128){
      const float* Fb = F + lane*2;
      for (; t+4 <= cnt; t += 4){
        float2 p0 = ws[wv][t+0], p1 = ws[wv][t+1];
        float2 p2 = ws[wv][t+2], p3 = ws[wv][t+3];
        float2 f0 = *(const float2*)(Fb + __float_as_int(p0.y)*128);
        float2 f1 = *(const float2*)(Fb + __float_as_int(p1.y)*128);
        float2 f2 = *(const float2*)(Fb + __float_as_int(p2.y)*128);
        float2 f3 = *(const float2*)(Fb + __float_as_int(p3.y)*128);
        acc0 = fmaf(p0.x, f0.x, acc0); acc1 = fmaf(p0.x, f0.y, acc1);
        acc0 = fmaf(p1.x, f1.x, acc0); acc1 = fmaf(p1.x, f1.y, acc1);
        acc0 = fmaf(p2.x, f2.x, acc0); acc1 = fmaf(p2.x, f2.y, acc1);
        acc0 = fmaf(p3.x, f3.x, acc0); acc1 = fmaf(p3.x, f3.y, acc1);
      }
      for (; t < cnt; ++t){
        float2 p = ws[wv][t];
        float2 f = *(const float2*)(Fb + __float_as_int(p.y)*128);
        acc0 = fmaf(p.x, f.x, acc0); acc1 = fmaf(p.x, f.y, acc1);
      }
    } else {
      const float* Fb = F + lane;
      for (; t+4 <= cnt; t += 4){
        float2 p0 = ws[wv][t+0], p1 = ws[wv][t+1];
        float2 p2 = ws[wv][t+2], p3 = ws[wv][t+3];
        float f0 = Fb[__float_as_int(p0.y)*64];
        float f1 = Fb[__float_as_int(p1.y)*64];
        float f2 = Fb[__float_as_int(p2.y)*64];
        float f3 = Fb[__float_as_int(p3.y)*64];
        acc0 = fmaf(p0.x, f0, acc0);
        acc0 = fmaf(p1.x, f1, acc0);
        acc0 = fmaf(p2.x, f2, acc0);
        acc0 = fmaf(p3.x, f3, acc0);
      }
      for (; t < cnt; ++t){
        float2 p = ws[wv][t];
        acc0 = fmaf(p.x, Fb[__float_as_int(p.y)*64], acc0);
      }
    }
    __builtin_amdgcn_wave_barrier();
  }

  const float zi = 1.f / fmaxf(z, 1e-9f);
  if (LOGSM){
    float y = acc0 * zi;
    float M = wave_max(y);
    float sum = wave_sum(__expf(y - M));
    out[(size_t)v*D + lane] = y - M - logf(sum);
  } else if (D == 128){
    float2 o;
    o.x = acc0*zi; o.y = acc1*zi;
    if (RELU){ o.x = fmaxf(o.x,0.f); o.y = fmaxf(o.y,0.f); }
    *(float2*)&out[(size_t)v*128 + lane*2] = o;
  } else {
    float o = acc0*zi;
    if (RELU) o = fmaxf(o,0.f);
    out[(size_t)v*64 + lane] = o;
  }
}

// ---------------- launch ----------------
extern "C" void kernel_launch(void* const* d_in, const int* in_sizes, int n_in,
                              void* d_out, int out_size, void* d_ws, size_t ws_size,
                              hipStream_t stream) {
  const float* h   = (const float*)d_in[0];
  const int*   src = (const int*)d_in[1];
  const int*   dst = (const int*)d_in[2];
  const float* W1  = (const float*)d_in[3];
  const float* al1 = (const float*)d_in[4];
  const float* ar1 = (const float*)d_in[5];
  const float* W2  = (const float*)d_in[6];
  const float* al2 = (const float*)d_in[7];
  const float* ar2 = (const float*)d_in[8];
  const float* W3  = (const float*)d_in[9];
  const float* al3 = (const float*)d_in[10];
  const float* ar3 = (const float*)d_in[11];

  const int N = in_sizes[0] / DIN;
  const int E = in_sizes[1];

  auto alignup = [](size_t x){ return (x + 255) & ~(size_t)255; };
  char* p = (char*)d_ws;
  int* counts  = (int*)p; p += alignup((size_t)N*4);
  int* offsets = (int*)p; p += alignup(((size_t)N+1)*4);
  int* cursor  = (int*)p; p += alignup((size_t)N*4);
  int* tmp     = (int*)p; p += alignup((size_t)N*4);
  int* bsum    = (int*)p; p += alignup(256*4);
  int* srcs    = (int*)p; p += alignup((size_t)E*4);
  float* F     = (float*)p; p += alignup((size_t)N*DHID*4);
  float* X     = (float*)p; p += alignup((size_t)N*DHID*4);
  float* el    = (float*)p; p += alignup((size_t)N*4);
  float* er    = (float*)p; p += alignup((size_t)N*4);
  unsigned short* Wp1 = (unsigned short*)p; p += alignup((size_t)2*DIN*DHID*2);
  unsigned short* Wp2 = (unsigned short*)p; p += alignup((size_t)2*DHID*DHID*2);
  unsigned short* Wp3 = (unsigned short*)p; p += alignup((size_t)2*DHID*DOUTC*2);

  const int nbN  = (N+255)/256;
  const int nbE  = (E+255)/256;
  const int nbW4 = (N+3)/4;
  const int nbG  = (N+63)/64;   // gemm_mfma: 64 rows/block

  // W pre-pack (independent of CSR build)
  pack_kernel<DIN ,DHID ><<<(DIN/32)*(DHID/16)*64/256,  256,0,stream>>>(W1, Wp1);
  pack_kernel<DHID,DHID ><<<(DHID/32)*(DHID/16)*64/256, 256,0,stream>>>(W2, Wp2);
  pack_kernel<DHID,DOUTC><<<(DHID/32)*(DOUTC/16)*64/256,256,0,stream>>>(W3, Wp3);

  hipMemsetAsync(counts, 0, (size_t)N*4, stream);
  hist_kernel<<<nbE,256,0,stream>>>(dst, counts, E);
  scan1_kernel<<<nbN,256,0,stream>>>(counts, tmp, bsum, N);
  scan2_kernel<<<1,256,0,stream>>>(bsum, nbN);
  scan3_kernel<<<nbN,256,0,stream>>>(tmp, bsum, offsets, cursor, N, E);
  scatter_kernel<<<nbE,256,0,stream>>>(src, dst, cursor, srcs, E);

  // Layer 1: [N,256]@[256,128]
  gemm_mfma<DIN,DHID><<<nbG,256,0,stream>>>(h, Wp1, al1, ar1, F, el, er, N);
  agg2_kernel<128,true,false><<<nbW4,256,0,stream>>>(F, el, er, offsets, srcs, X, N);

  // Layer 2: [N,128]@[128,128]
  gemm_mfma<DHID,DHID><<<nbG,256,0,stream>>>(X, Wp2, al2, ar2, F, el, er, N);
  agg2_kernel<128,true,false><<<nbW4,256,0,stream>>>(F, el, er, offsets, srcs, X, N);

  // Layer 3: [N,128]@[128,64] + log_softmax
  gemm_mfma<DHID,DOUTC><<<nbG,256,0,stream>>>(X, Wp3, al3, ar3, F, el, er, N);
  agg2_kernel<64,false,true><<<nbW4,256,0,stream>>>(F, el, er, offsets, srcs, (float*)d_out, N);
}

// Round 4
// 266.963 us; speedup vs baseline: 1.9427x; 1.2084x over previous
//
#include <hip/hip_runtime.h>
#include <math.h>

#define DIN 256
#define DHID 128
#define DOUTC 64

typedef __attribute__((ext_vector_type(8))) short short8;
typedef __attribute__((ext_vector_type(4))) float f32x4;

static __device__ __forceinline__ float wave_max(float v){
  #pragma unroll
  for (int o=1;o<64;o<<=1) v = fmaxf(v, __shfl_xor(v,o,64));
  return v;
}
static __device__ __forceinline__ float wave_sum(float v){
  #pragma unroll
  for (int o=1;o<64;o<<=1) v += __shfl_xor(v,o,64);
  return v;
}

static __device__ __forceinline__ unsigned short bf16_rne(float x){
  unsigned int u = __float_as_uint(x);
  return (unsigned short)((u + 0x7FFFu + ((u>>16)&1u)) >> 16);
}
static __device__ __forceinline__ float bf16_to_f32(unsigned short h){
  return __uint_as_float(((unsigned int)h)<<16);
}
static __device__ __forceinline__ float blo(unsigned int u){ return __uint_as_float(u<<16); }
static __device__ __forceinline__ float bhi(unsigned int u){ return __uint_as_float(u & 0xffff0000u); }

// ---------------- CSR build ----------------
__global__ void hist_kernel(const int* __restrict__ dst, int* __restrict__ counts, int E){
  int i = blockIdx.x*256 + threadIdx.x;
  if (i < E) atomicAdd(&counts[dst[i]], 1);
}

__global__ void scan1_kernel(const int* __restrict__ counts, int* __restrict__ tmp,
                             int* __restrict__ bsum, int N){
  __shared__ int b[256];
  int t = threadIdx.x;
  int i = blockIdx.x*256 + t;
  int v = (i<N)? counts[i] : 0;
  b[t] = v; __syncthreads();
  #pragma unroll
  for (int o=1;o<256;o<<=1){
    int x = (t>=o)? b[t-o] : 0;
    __syncthreads();
    b[t] += x;
    __syncthreads();
  }
  if (i<N) tmp[i] = b[t]-v;
  if (t==255) bsum[blockIdx.x] = b[255];
}

__global__ void scan2_kernel(int* __restrict__ bsum, int nb){
  __shared__ int b[256];
  int t = threadIdx.x;
  int v = (t<nb)? bsum[t] : 0;
  b[t]=v; __syncthreads();
  #pragma unroll
  for (int o=1;o<256;o<<=1){
    int x = (t>=o)? b[t-o] : 0;
    __syncthreads();
    b[t] += x;
    __syncthreads();
  }
  if (t<nb) bsum[t] = b[t]-v;
}

__global__ void scan3_kernel(const int* __restrict__ tmp, const int* __restrict__ bsum,
                             int* __restrict__ offsets, int* __restrict__ cursor, int N, int E){
  int i = blockIdx.x*256 + threadIdx.x;
  if (i<N){ int o = tmp[i] + bsum[blockIdx.x]; offsets[i]=o; cursor[i]=o; }
  if (i==0) offsets[N]=E;
}

__global__ void scatter_kernel(const int* __restrict__ src, const int* __restrict__ dst,
                               int* __restrict__ cursor, int* __restrict__ srcs, int E){
  int i = blockIdx.x*256 + threadIdx.x;
  if (i < E){
    int pos = atomicAdd(&cursor[dst[i]], 1);
    srcs[pos] = src[i];
  }
}

// ---- pack W into MFMA B-fragment order, bf16 hi/lo interleaved (16+16 shorts/lane) ----
template<int K, int NC>
__global__ void pack_kernel(const float* __restrict__ W, unsigned short* __restrict__ Wp){
  constexpr int CT = NC/16, KT = K/32;
  int idx = blockIdx.x*256 + threadIdx.x;
  if (idx >= KT*CT*64) return;
  int l = idx & 63, t = idx >> 6;
  int ct = t % CT, kt = t / CT;
  int col = ct*16 + (l & 15);
  int k0 = kt*32 + (l >> 4)*8;
  unsigned short* dstp = Wp + (size_t)idx*16;
  #pragma unroll
  for (int j=0;j<8;j++){
    float x = W[(size_t)(k0+j)*NC + col];
    unsigned short h = bf16_rne(x);
    dstp[j] = h;
    dstp[8+j] = bf16_rne(x - bf16_to_f32(h));
  }
}

// ---- MFMA GEMM (bf16x3, fp32-class precision) + fused el/er; writes bf16 F ----
template<int K, int NC>
__global__ __launch_bounds__(256) void gemm_mfma(const float* __restrict__ A,
    const unsigned short* __restrict__ Wp,
    const float* __restrict__ al, const float* __restrict__ ar,
    unsigned short* __restrict__ Fb, float* __restrict__ el, float* __restrict__ er, int nrows)
{
  constexpr int CT = NC/16, KT = K/32;
  const int lane = threadIdx.x & 63;
  const int wid  = threadIdx.x >> 6;
  const int row0 = blockIdx.x*64 + wid*16;
  const int c = lane & 15, g = lane >> 4;
  const int arow = row0 + c;
  const bool aok = arow < nrows;

  f32x4 acc[CT];
  #pragma unroll
  for (int i=0;i<CT;i++) acc[i] = (f32x4)0.f;

  #pragma unroll
  for (int kt=0; kt<KT; ++kt){
    const int k0 = kt*32 + g*8;
    float xs[8];
    if (aok){
      float4 v0 = *(const float4*)&A[(size_t)arow*K + k0];
      float4 v1 = *(const float4*)&A[(size_t)arow*K + k0 + 4];
      xs[0]=v0.x; xs[1]=v0.y; xs[2]=v0.z; xs[3]=v0.w;
      xs[4]=v1.x; xs[5]=v1.y; xs[6]=v1.z; xs[7]=v1.w;
    } else {
      #pragma unroll
      for (int j=0;j<8;j++) xs[j]=0.f;
    }
    short8 ahi, alo;
    #pragma unroll
    for (int j=0;j<8;j++){
      unsigned short h = bf16_rne(xs[j]);
      ahi[j] = (short)h;
      alo[j] = (short)bf16_rne(xs[j] - bf16_to_f32(h));
    }
    #pragma unroll
    for (int ct=0; ct<CT; ++ct){
      const size_t base = ((size_t)((kt*CT+ct)*64 + lane))*16;
      short8 bhi8 = *(const short8*)&Wp[base];
      short8 blo8 = *(const short8*)&Wp[base+8];
      acc[ct] = __builtin_amdgcn_mfma_f32_16x16x32_bf16(ahi, bhi8, acc[ct], 0,0,0);
      acc[ct] = __builtin_amdgcn_mfma_f32_16x16x32_bf16(alo, bhi8, acc[ct], 0,0,0);
      acc[ct] = __builtin_amdgcn_mfma_f32_16x16x32_bf16(ahi, blo8, acc[ct], 0,0,0);
    }
  }

  // epilogue: C/D layout row=(lane>>4)*4+j, col=lane&15. Store bf16 F + fused el/er.
  float alv[CT], arv[CT];
  #pragma unroll
  for (int ct=0;ct<CT;ct++){ alv[ct]=al[ct*16+c]; arv[ct]=ar[ct*16+c]; }
  #pragma unroll
  for (int j=0;j<4;j++){
    const int row = row0 + g*4 + j;
    const bool ok = row < nrows;
    float sl=0.f, sr=0.f;
    #pragma unroll
    for (int ct=0;ct<CT;ct++){
      float f = acc[ct][j];
      sl = fmaf(f, alv[ct], sl);
      sr = fmaf(f, arv[ct], sr);
      if (ok) Fb[(size_t)row*NC + ct*16 + c] = bf16_rne(f);
    }
    #pragma unroll
    for (int o=1;o<16;o<<=1){ sl += __shfl_xor(sl,o,64); sr += __shfl_xor(sr,o,64); }
    if (ok && c==0){ el[row]=sl; er[row]=sr; }
  }
}

// ---------------- per-node online edge softmax + aggregate ----------------
// One wave per node. Lane-parallel weight phase (64 edges/chunk), then the 4
// 16-lane groups each aggregate a strided quarter of the chunk with 16-lane-wide
// bf16 row reads. Cross-group shfl reduce at the end.
template<int D, bool RELU, bool LOGSM>
__global__ __launch_bounds__(256) void agg3_kernel(const unsigned short* __restrict__ Fb,
    const float* __restrict__ el, const float* __restrict__ er,
    const int* __restrict__ offsets, const int* __restrict__ srcs,
    float* __restrict__ out, int N)
{
  constexpr int CPL = D/16;             // cols per lane: 8 (D=128) or 4 (D=64)
  __shared__ float2 ws[4][64];
  const int wv = threadIdx.x >> 6;
  const int lane = threadIdx.x & 63;
  const int c16 = lane & 15, g = lane >> 4;
  const int v = blockIdx.x*4 + wv;
  if (v >= N) return;
  const int o0 = offsets[v], o1 = offsets[v+1];
  const float erv = er[v];

  float m = -INFINITY, z = 0.f;
  float acc[CPL];
  #pragma unroll
  for (int i=0;i<CPL;i++) acc[i]=0.f;

  for (int s0 = o0; s0 < o1; s0 += 64){
    const int j = s0 + lane;
    int sidx = 0; float e = -INFINITY;
    if (j < o1){
      sidx = srcs[j];
      float tv = el[sidx] + erv;
      e = (tv > 0.f) ? tv : 0.2f*tv;
    }
    const float nm = fmaxf(m, wave_max(e));
    const float scale = __expf(m - nm);
    const float wgt = __expf(e - nm);
    z = z*scale + wave_sum(wgt);
    #pragma unroll
    for (int i=0;i<CPL;i++) acc[i] *= scale;
    m = nm;
    ws[wv][lane] = make_float2(wgt, __int_as_float(sidx));
    __builtin_amdgcn_wave_barrier();

    const int cnt = min(64, o1 - s0);
    int t = g;
    if (D == 128){
      for (; t+4 < cnt; t += 8){
        float2 p0 = ws[wv][t], p1 = ws[wv][t+4];
        uint4 u0 = *((const uint4*)(Fb + (size_t)__float_as_int(p0.y)*128) + c16);
        uint4 u1 = *((const uint4*)(Fb + (size_t)__float_as_int(p1.y)*128) + c16);
        acc[0]=fmaf(p0.x, blo(u0.x), acc[0]); acc[1]=fmaf(p0.x, bhi(u0.x), acc[1]);
        acc[2]=fmaf(p0.x, blo(u0.y), acc[2]); acc[3]=fmaf(p0.x, bhi(u0.y), acc[3]);
        acc[4]=fmaf(p0.x, blo(u0.z), acc[4]); acc[5]=fmaf(p0.x, bhi(u0.z), acc[5]);
        acc[6]=fmaf(p0.x, blo(u0.w), acc[6]); acc[7]=fmaf(p0.x, bhi(u0.w), acc[7]);
        acc[0]=fmaf(p1.x, blo(u1.x), acc[0]); acc[1]=fmaf(p1.x, bhi(u1.x), acc[1]);
        acc[2]=fmaf(p1.x, blo(u1.y), acc[2]); acc[3]=fmaf(p1.x, bhi(u1.y), acc[3]);
        acc[4]=fmaf(p1.x, blo(u1.z), acc[4]); acc[5]=fmaf(p1.x, bhi(u1.z), acc[5]);
        acc[6]=fmaf(p1.x, blo(u1.w), acc[6]); acc[7]=fmaf(p1.x, bhi(u1.w), acc[7]);
      }
      if (t < cnt){
        float2 p0 = ws[wv][t];
        uint4 u0 = *((const uint4*)(Fb + (size_t)__float_as_int(p0.y)*128) + c16);
        acc[0]=fmaf(p0.x, blo(u0.x), acc[0]); acc[1]=fmaf(p0.x, bhi(u0.x), acc[1]);
        acc[2]=fmaf(p0.x, blo(u0.y), acc[2]); acc[3]=fmaf(p0.x, bhi(u0.y), acc[3]);
        acc[4]=fmaf(p0.x, blo(u0.z), acc[4]); acc[5]=fmaf(p0.x, bhi(u0.z), acc[5]);
        acc[6]=fmaf(p0.x, blo(u0.w), acc[6]); acc[7]=fmaf(p0.x, bhi(u0.w), acc[7]);
      }
    } else {
      for (; t+4 < cnt; t += 8){
        float2 p0 = ws[wv][t], p1 = ws[wv][t+4];
        uint2 u0 = *((const uint2*)(Fb + (size_t)__float_as_int(p0.y)*64) + c16);
        uint2 u1 = *((const uint2*)(Fb + (size_t)__float_as_int(p1.y)*64) + c16);
        acc[0]=fmaf(p0.x, blo(u0.x), acc[0]); acc[1]=fmaf(p0.x, bhi(u0.x), acc[1]);
        acc[2]=fmaf(p0.x, blo(u0.y), acc[2]); acc[3]=fmaf(p0.x, bhi(u0.y), acc[3]);
        acc[0]=fmaf(p1.x, blo(u1.x), acc[0]); acc[1]=fmaf(p1.x, bhi(u1.x), acc[1]);
        acc[2]=fmaf(p1.x, blo(u1.y), acc[2]); acc[3]=fmaf(p1.x, bhi(u1.y), acc[3]);
      }
      if (t < cnt){
        float2 p0 = ws[wv][t];
        uint2 u0 = *((const uint2*)(Fb + (size_t)__float_as_int(p0.y)*64) + c16);
        acc[0]=fmaf(p0.x, blo(u0.x), acc[0]); acc[1]=fmaf(p0.x, bhi(u0.x), acc[1]);
        acc[2]=fmaf(p0.x, blo(u0.y), acc[2]); acc[3]=fmaf(p0.x, bhi(u0.y), acc[3]);
      }
    }
    __builtin_amdgcn_wave_barrier();
  }

  // combine the 4 groups (lane bits 4,5)
  #pragma unroll
  for (int i=0;i<CPL;i++){
    acc[i] += __shfl_xor(acc[i],16,64);
    acc[i] += __shfl_xor(acc[i],32,64);
  }
  const float zi = 1.f / fmaxf(z, 1e-9f);

  if (LOGSM){
    float y[CPL];
    #pragma unroll
    for (int i=0;i<CPL;i++) y[i] = acc[i]*zi;
    float M = y[0];
    #pragma unroll
    for (int i=1;i<CPL;i++) M = fmaxf(M, y[i]);
    #pragma unroll
    for (int o=1;o<16;o<<=1) M = fmaxf(M, __shfl_xor(M,o,64));
    float ssum = 0.f;
    #pragma unroll
    for (int i=0;i<CPL;i++) ssum += __expf(y[i]-M);
    #pragma unroll
    for (int o=1;o<16;o<<=1) ssum += __shfl_xor(ssum,o,64);
    const float lw = M + logf(ssum);
    if (g==0){
      float4 r = make_float4(y[0]-lw, y[1]-lw, y[2]-lw, y[3]-lw);
      *(float4*)&out[(size_t)v*64 + c16*4] = r;
    }
  } else {
    if (g==0){
      float r[CPL];
      #pragma unroll
      for (int i=0;i<CPL;i++){ r[i]=acc[i]*zi; if (RELU) r[i]=fmaxf(r[i],0.f); }
      *(float4*)&out[(size_t)v*128 + c16*8]     = make_float4(r[0],r[1],r[2],r[3]);
      *(float4*)&out[(size_t)v*128 + c16*8 + 4] = make_float4(r[4],r[5],r[6],r[7]);
    }
  }
}

// ---------------- launch ----------------
extern "C" void kernel_launch(void* const* d_in, const int* in_sizes, int n_in,
                              void* d_out, int out_size, void* d_ws, size_t ws_size,
                              hipStream_t stream) {
  const float* h   = (const float*)d_in[0];
  const int*   src = (const int*)d_in[1];
  const int*   dst = (const int*)d_in[2];
  const float* W1  = (const float*)d_in[3];
  const float* al1 = (const float*)d_in[4];
  const float* ar1 = (const float*)d_in[5];
  const float* W2  = (const float*)d_in[6];
  const float* al2 = (const float*)d_in[7];
  const float* ar2 = (const float*)d_in[8];
  const float* W3  = (const float*)d_in[9];
  const float* al3 = (const float*)d_in[10];
  const float* ar3 = (const float*)d_in[11];

  const int N = in_sizes[0] / DIN;
  const int E = in_sizes[1];

  auto alignup = [](size_t x){ return (x + 255) & ~(size_t)255; };
  char* p = (char*)d_ws;
  int* counts  = (int*)p; p += alignup((size_t)N*4);
  int* offsets = (int*)p; p += alignup(((size_t)N+1)*4);
  int* cursor  = (int*)p; p += alignup((size_t)N*4);
  int* tmp     = (int*)p; p += alignup((size_t)N*4);
  int* bsum    = (int*)p; p += alignup(256*4);
  int* srcs    = (int*)p; p += alignup((size_t)E*4);
  unsigned short* Fb = (unsigned short*)p; p += alignup((size_t)N*DHID*2);
  float* X     = (float*)p; p += alignup((size_t)N*DHID*4);
  float* el    = (float*)p; p += alignup((size_t)N*4);
  float* er    = (float*)p; p += alignup((size_t)N*4);
  unsigned short* Wp1 = (unsigned short*)p; p += alignup((size_t)2*DIN*DHID*2);
  unsigned short* Wp2 = (unsigned short*)p; p += alignup((size_t)2*DHID*DHID*2);
  unsigned short* Wp3 = (unsigned short*)p; p += alignup((size_t)2*DHID*DOUTC*2);

  const int nbN  = (N+255)/256;
  const int nbE  = (E+255)/256;
  const int nbW4 = (N+3)/4;
  const int nbG  = (N+63)/64;

  pack_kernel<DIN ,DHID ><<<(DIN/32)*(DHID/16)*64/256,  256,0,stream>>>(W1, Wp1);
  pack_kernel<DHID,DHID ><<<(DHID/32)*(DHID/16)*64/256, 256,0,stream>>>(W2, Wp2);
  pack_kernel<DHID,DOUTC><<<(DHID/32)*(DOUTC/16)*64/256,256,0,stream>>>(W3, Wp3);

  hipMemsetAsync(counts, 0, (size_t)N*4, stream);
  hist_kernel<<<nbE,256,0,stream>>>(dst, counts, E);
  scan1_kernel<<<nbN,256,0,stream>>>(counts, tmp, bsum, N);
  scan2_kernel<<<1,256,0,stream>>>(bsum, nbN);
  scan3_kernel<<<nbN,256,0,stream>>>(tmp, bsum, offsets, cursor, N, E);
  scatter_kernel<<<nbE,256,0,stream>>>(src, dst, cursor, srcs, E);

  // Layer 1: [N,256]@[256,128]
  gemm_mfma<DIN,DHID><<<nbG,256,0,stream>>>(h, Wp1, al1, ar1, Fb, el, er, N);
  agg3_kernel<128,true,false><<<nbW4,256,0,stream>>>(Fb, el, er, offsets, srcs, X, N);

  // Layer 2: [N,128]@[128,128]
  gemm_mfma<DHID,DHID><<<nbG,256,0,stream>>>(X, Wp2, al2, ar2, Fb, el, er, N);
  agg3_kernel<128,true,false><<<nbW4,256,0,stream>>>(Fb, el, er, offsets, srcs, X, N);

  // Layer 3: [N,128]@[128,64] + log_softmax
  gemm_mfma<DHID,DOUTC><<<nbG,256,0,stream>>>(X, Wp3, al3, ar3, Fb, el, er, N);
  agg3_kernel<64,false,true><<<nbW4,256,0,stream>>>(Fb, el, er, offsets, srcs, (float*)d_out, N);
}

// Round 5
// 202.177 us; speedup vs baseline: 2.5653x; 1.3204x over previous
//
#include <hip/hip_runtime.h>
#include <math.h>

#define DIN 256
#define DHID 128
#define DOUTC 64
#define EPB 2048   // edges per block in bucket phase 1

typedef __attribute__((ext_vector_type(8))) short short8;
typedef __attribute__((ext_vector_type(4))) float f32x4;

static __device__ __forceinline__ float wave_max(float v){
  #pragma unroll
  for (int o=1;o<64;o<<=1) v = fmaxf(v, __shfl_xor(v,o,64));
  return v;
}
static __device__ __forceinline__ float wave_sum(float v){
  #pragma unroll
  for (int o=1;o<64;o<<=1) v += __shfl_xor(v,o,64);
  return v;
}

static __device__ __forceinline__ unsigned short bf16_rne(float x){
  unsigned int u = __float_as_uint(x);
  return (unsigned short)((u + 0x7FFFu + ((u>>16)&1u)) >> 16);
}
static __device__ __forceinline__ float bf16_to_f32(unsigned short h){
  return __uint_as_float(((unsigned int)h)<<16);
}
static __device__ __forceinline__ float blo(unsigned int u){ return __uint_as_float(u<<16); }
static __device__ __forceinline__ float bhi(unsigned int u){ return __uint_as_float(u & 0xffff0000u); }

// ================= CSR build: atomic-free 2-phase MSD bucket sort =================
// Phase 1: bucket edges by hb = dst>>8 (bin-major hist table, scan, LDS-cursor scatter)
__global__ __launch_bounds__(256) void rs_hist(const int* __restrict__ dst,
    int* __restrict__ ghist, int E, int NB){
  __shared__ int h[256];
  const int t = threadIdx.x, blk = blockIdx.x;
  h[t] = 0; __syncthreads();
  const int base = blk*EPB;
  #pragma unroll
  for (int i=0;i<EPB/256;i++){
    int j = base + i*256 + t;
    if (j < E) atomicAdd(&h[dst[j]>>8], 1);
  }
  __syncthreads();
  ghist[t*NB + blk] = h[t];
}

__global__ __launch_bounds__(256) void rs_scan(int* __restrict__ ghist,
    int* __restrict__ btot, int NB){
  __shared__ int b[256];
  __shared__ int carry;
  const int hb = blockIdx.x, t = threadIdx.x;
  if (t==0) carry = 0;
  __syncthreads();
  for (int c0=0; c0<NB; c0+=256){
    int i = c0 + t;
    int v = (i<NB)? ghist[hb*NB+i] : 0;
    b[t] = v; __syncthreads();
    #pragma unroll
    for (int o=1;o<256;o<<=1){
      int x = (t>=o)? b[t-o] : 0;
      __syncthreads();
      b[t] += x;
      __syncthreads();
    }
    if (i<NB) ghist[hb*NB+i] = carry + b[t] - v;   // exclusive
    __syncthreads();
    if (t==255) carry += b[255];
    __syncthreads();
  }
  if (t==255) btot[hb] = carry;
}

__global__ __launch_bounds__(256) void rs_scan2(int* __restrict__ btot,
    int* __restrict__ offsets, int N, int E){
  __shared__ int b[256];
  const int t = threadIdx.x;
  int v = btot[t];
  b[t] = v; __syncthreads();
  #pragma unroll
  for (int o=1;o<256;o<<=1){
    int x = (t>=o)? b[t-o] : 0;
    __syncthreads();
    b[t] += x;
    __syncthreads();
  }
  btot[t] = b[t] - v;                 // exclusive bucket bases
  if (t==255){ btot[256] = E; offsets[N] = E; }
}

__global__ __launch_bounds__(256) void rs_scatter(const int* __restrict__ src,
    const int* __restrict__ dst, const int* __restrict__ ghist,
    const int* __restrict__ btot, uint2* __restrict__ ebuf, int E, int NB){
  __shared__ int cur[256];
  const int t = threadIdx.x, blk = blockIdx.x;
  cur[t] = ghist[t*NB + blk] + btot[t];
  __syncthreads();
  const int base = blk*EPB;
  #pragma unroll
  for (int i=0;i<EPB/256;i++){
    int j = base + i*256 + t;
    if (j < E){
      int d = dst[j];
      int pos = atomicAdd(&cur[d>>8], 1);
      ebuf[pos] = make_uint2((unsigned)src[j], (unsigned)d);
    }
  }
}

// Phase 2: per-bucket exact counting sort on dst&255; emits grouped srcs + offsets
__global__ __launch_bounds__(256) void bucket_sort(const uint2* __restrict__ ebuf,
    const int* __restrict__ btot, int* __restrict__ offsets,
    int* __restrict__ srcs, int N){
  __shared__ int h[256];
  __shared__ int b[256];
  const int hb = blockIdx.x, t = threadIdx.x;
  const int b0 = btot[hb], b1 = btot[hb+1];
  h[t] = 0; __syncthreads();
  for (int j=b0+t; j<b1; j+=256) atomicAdd(&h[ebuf[j].y & 255u], 1);
  __syncthreads();
  int v = h[t];
  b[t] = v; __syncthreads();
  #pragma unroll
  for (int o=1;o<256;o<<=1){
    int x = (t>=o)? b[t-o] : 0;
    __syncthreads();
    b[t] += x;
    __syncthreads();
  }
  const int excl = b[t] - v;
  const int node = hb*256 + t;
  if (node < N) offsets[node] = b0 + excl;
  h[t] = excl;                         // cursors
  __syncthreads();
  for (int j=b0+t; j<b1; j+=256){
    uint2 e = ebuf[j];
    int pos = b0 + atomicAdd(&h[e.y & 255u], 1);
    srcs[pos] = (int)e.x;
  }
}

// ---- pack W into MFMA B-fragment order, bf16 hi/lo interleaved (16+16 shorts/lane) ----
template<int K, int NC>
__global__ void pack_kernel(const float* __restrict__ W, unsigned short* __restrict__ Wp){
  constexpr int CT = NC/16, KT = K/32;
  int idx = blockIdx.x*256 + threadIdx.x;
  if (idx >= KT*CT*64) return;
  int l = idx & 63, t = idx >> 6;
  int ct = t % CT, kt = t / CT;
  int col = ct*16 + (l & 15);
  int k0 = kt*32 + (l >> 4)*8;
  unsigned short* dstp = Wp + (size_t)idx*16;
  #pragma unroll
  for (int j=0;j<8;j++){
    float x = W[(size_t)(k0+j)*NC + col];
    unsigned short h = bf16_rne(x);
    dstp[j] = h;
    dstp[8+j] = bf16_rne(x - bf16_to_f32(h));
  }
}

// ---- MFMA GEMM (bf16x3, fp32-class precision) + fused el/er; writes bf16 F ----
template<int K, int NC>
__global__ __launch_bounds__(256) void gemm_mfma(const float* __restrict__ A,
    const unsigned short* __restrict__ Wp,
    const float* __restrict__ al, const float* __restrict__ ar,
    unsigned short* __restrict__ Fb, float* __restrict__ el, float* __restrict__ er, int nrows)
{
  constexpr int CT = NC/16, KT = K/32;
  const int lane = threadIdx.x & 63;
  const int wid  = threadIdx.x >> 6;
  const int row0 = blockIdx.x*64 + wid*16;
  const int c = lane & 15, g = lane >> 4;
  const int arow = row0 + c;
  const bool aok = arow < nrows;

  f32x4 acc[CT];
  #pragma unroll
  for (int i=0;i<CT;i++) acc[i] = (f32x4)0.f;

  #pragma unroll
  for (int kt=0; kt<KT; ++kt){
    const int k0 = kt*32 + g*8;
    float xs[8];
    if (aok){
      float4 v0 = *(const float4*)&A[(size_t)arow*K + k0];
      float4 v1 = *(const float4*)&A[(size_t)arow*K + k0 + 4];
      xs[0]=v0.x; xs[1]=v0.y; xs[2]=v0.z; xs[3]=v0.w;
      xs[4]=v1.x; xs[5]=v1.y; xs[6]=v1.z; xs[7]=v1.w;
    } else {
      #pragma unroll
      for (int j=0;j<8;j++) xs[j]=0.f;
    }
    short8 ahi, alo;
    #pragma unroll
    for (int j=0;j<8;j++){
      unsigned short h = bf16_rne(xs[j]);
      ahi[j] = (short)h;
      alo[j] = (short)bf16_rne(xs[j] - bf16_to_f32(h));
    }
    #pragma unroll
    for (int ct=0; ct<CT; ++ct){
      const size_t base = ((size_t)((kt*CT+ct)*64 + lane))*16;
      short8 bhi8 = *(const short8*)&Wp[base];
      short8 blo8 = *(const short8*)&Wp[base+8];
      acc[ct] = __builtin_amdgcn_mfma_f32_16x16x32_bf16(ahi, bhi8, acc[ct], 0,0,0);
      acc[ct] = __builtin_amdgcn_mfma_f32_16x16x32_bf16(alo, bhi8, acc[ct], 0,0,0);
      acc[ct] = __builtin_amdgcn_mfma_f32_16x16x32_bf16(ahi, blo8, acc[ct], 0,0,0);
    }
  }

  float alv[CT], arv[CT];
  #pragma unroll
  for (int ct=0;ct<CT;ct++){ alv[ct]=al[ct*16+c]; arv[ct]=ar[ct*16+c]; }
  #pragma unroll
  for (int j=0;j<4;j++){
    const int row = row0 + g*4 + j;
    const bool ok = row < nrows;
    float sl=0.f, sr=0.f;
    #pragma unroll
    for (int ct=0;ct<CT;ct++){
      float f = acc[ct][j];
      sl = fmaf(f, alv[ct], sl);
      sr = fmaf(f, arv[ct], sr);
      if (ok) Fb[(size_t)row*NC + ct*16 + c] = bf16_rne(f);
    }
    #pragma unroll
    for (int o=1;o<16;o<<=1){ sl += __shfl_xor(sl,o,64); sr += __shfl_xor(sr,o,64); }
    if (ok && c==0){ el[row]=sl; er[row]=sr; }
  }
}

// ---------------- per-node online edge softmax + aggregate ----------------
template<int D, bool RELU, bool LOGSM>
__global__ __launch_bounds__(256) void agg3_kernel(const unsigned short* __restrict__ Fb,
    const float* __restrict__ el, const float* __restrict__ er,
    const int* __restrict__ offsets, const int* __restrict__ srcs,
    float* __restrict__ out, int N)
{
  constexpr int CPL = D/16;
  __shared__ float2 ws[4][64];
  const int wv = threadIdx.x >> 6;
  const int lane = threadIdx.x & 63;
  const int c16 = lane & 15, g = lane >> 4;
  const int v = blockIdx.x*4 + wv;
  if (v >= N) return;
  const int o0 = offsets[v], o1 = offsets[v+1];
  const float erv = er[v];

  float m = -INFINITY, z = 0.f;
  float acc[CPL];
  #pragma unroll
  for (int i=0;i<CPL;i++) acc[i]=0.f;

  for (int s0 = o0; s0 < o1; s0 += 64){
    const int j = s0 + lane;
    int sidx = 0; float e = -INFINITY;
    if (j < o1){
      sidx = srcs[j];
      float tv = el[sidx] + erv;
      e = (tv > 0.f) ? tv : 0.2f*tv;
    }
    const float nm = fmaxf(m, wave_max(e));
    const float scale = __expf(m - nm);
    const float wgt = __expf(e - nm);
    z = z*scale + wave_sum(wgt);
    #pragma unroll
    for (int i=0;i<CPL;i++) acc[i] *= scale;
    m = nm;
    ws[wv][lane] = make_float2(wgt, __int_as_float(sidx));
    __builtin_amdgcn_wave_barrier();

    const int cnt = min(64, o1 - s0);
    int t = g;
    if (D == 128){
      for (; t+4 < cnt; t += 8){
        float2 p0 = ws[wv][t], p1 = ws[wv][t+4];
        uint4 u0 = *((const uint4*)(Fb + (size_t)__float_as_int(p0.y)*128) + c16);
        uint4 u1 = *((const uint4*)(Fb + (size_t)__float_as_int(p1.y)*128) + c16);
        acc[0]=fmaf(p0.x, blo(u0.x), acc[0]); acc[1]=fmaf(p0.x, bhi(u0.x), acc[1]);
        acc[2]=fmaf(p0.x, blo(u0.y), acc[2]); acc[3]=fmaf(p0.x, bhi(u0.y), acc[3]);
        acc[4]=fmaf(p0.x, blo(u0.z), acc[4]); acc[5]=fmaf(p0.x, bhi(u0.z), acc[5]);
        acc[6]=fmaf(p0.x, blo(u0.w), acc[6]); acc[7]=fmaf(p0.x, bhi(u0.w), acc[7]);
        acc[0]=fmaf(p1.x, blo(u1.x), acc[0]); acc[1]=fmaf(p1.x, bhi(u1.x), acc[1]);
        acc[2]=fmaf(p1.x, blo(u1.y), acc[2]); acc[3]=fmaf(p1.x, bhi(u1.y), acc[3]);
        acc[4]=fmaf(p1.x, blo(u1.z), acc[4]); acc[5]=fmaf(p1.x, bhi(u1.z), acc[5]);
        acc[6]=fmaf(p1.x, blo(u1.w), acc[6]); acc[7]=fmaf(p1.x, bhi(u1.w), acc[7]);
      }
      if (t < cnt){
        float2 p0 = ws[wv][t];
        uint4 u0 = *((const uint4*)(Fb + (size_t)__float_as_int(p0.y)*128) + c16);
        acc[0]=fmaf(p0.x, blo(u0.x), acc[0]); acc[1]=fmaf(p0.x, bhi(u0.x), acc[1]);
        acc[2]=fmaf(p0.x, blo(u0.y), acc[2]); acc[3]=fmaf(p0.x, bhi(u0.y), acc[3]);
        acc[4]=fmaf(p0.x, blo(u0.z), acc[4]); acc[5]=fmaf(p0.x, bhi(u0.z), acc[5]);
        acc[6]=fmaf(p0.x, blo(u0.w), acc[6]); acc[7]=fmaf(p0.x, bhi(u0.w), acc[7]);
      }
    } else {
      for (; t+4 < cnt; t += 8){
        float2 p0 = ws[wv][t], p1 = ws[wv][t+4];
        uint2 u0 = *((const uint2*)(Fb + (size_t)__float_as_int(p0.y)*64) + c16);
        uint2 u1 = *((const uint2*)(Fb + (size_t)__float_as_int(p1.y)*64) + c16);
        acc[0]=fmaf(p0.x, blo(u0.x), acc[0]); acc[1]=fmaf(p0.x, bhi(u0.x), acc[1]);
        acc[2]=fmaf(p0.x, blo(u0.y), acc[2]); acc[3]=fmaf(p0.x, bhi(u0.y), acc[3]);
        acc[0]=fmaf(p1.x, blo(u1.x), acc[0]); acc[1]=fmaf(p1.x, bhi(u1.x), acc[1]);
        acc[2]=fmaf(p1.x, blo(u1.y), acc[2]); acc[3]=fmaf(p1.x, bhi(u1.y), acc[3]);
      }
      if (t < cnt){
        float2 p0 = ws[wv][t];
        uint2 u0 = *((const uint2*)(Fb + (size_t)__float_as_int(p0.y)*64) + c16);
        acc[0]=fmaf(p0.x, blo(u0.x), acc[0]); acc[1]=fmaf(p0.x, bhi(u0.x), acc[1]);
        acc[2]=fmaf(p0.x, blo(u0.y), acc[2]); acc[3]=fmaf(p0.x, bhi(u0.y), acc[3]);
      }
    }
    __builtin_amdgcn_wave_barrier();
  }

  #pragma unroll
  for (int i=0;i<CPL;i++){
    acc[i] += __shfl_xor(acc[i],16,64);
    acc[i] += __shfl_xor(acc[i],32,64);
  }
  const float zi = 1.f / fmaxf(z, 1e-9f);

  if (LOGSM){
    float y[CPL];
    #pragma unroll
    for (int i=0;i<CPL;i++) y[i] = acc[i]*zi;
    float M = y[0];
    #pragma unroll
    for (int i=1;i<CPL;i++) M = fmaxf(M, y[i]);
    #pragma unroll
    for (int o=1;o<16;o<<=1) M = fmaxf(M, __shfl_xor(M,o,64));
    float ssum = 0.f;
    #pragma unroll
    for (int i=0;i<CPL;i++) ssum += __expf(y[i]-M);
    #pragma unroll
    for (int o=1;o<16;o<<=1) ssum += __shfl_xor(ssum,o,64);
    const float lw = M + logf(ssum);
    if (g==0){
      float4 r = make_float4(y[0]-lw, y[1]-lw, y[2]-lw, y[3]-lw);
      *(float4*)&out[(size_t)v*64 + c16*4] = r;
    }
  } else {
    if (g==0){
      float r[CPL];
      #pragma unroll
      for (int i=0;i<CPL;i++){ r[i]=acc[i]*zi; if (RELU) r[i]=fmaxf(r[i],0.f); }
      *(float4*)&out[(size_t)v*128 + c16*8]     = make_float4(r[0],r[1],r[2],r[3]);
      *(float4*)&out[(size_t)v*128 + c16*8 + 4] = make_float4(r[4],r[5],r[6],r[7]);
    }
  }
}

// ---------------- launch ----------------
extern "C" void kernel_launch(void* const* d_in, const int* in_sizes, int n_in,
                              void* d_out, int out_size, void* d_ws, size_t ws_size,
                              hipStream_t stream) {
  const float* h   = (const float*)d_in[0];
  const int*   src = (const int*)d_in[1];
  const int*   dst = (const int*)d_in[2];
  const float* W1  = (const float*)d_in[3];
  const float* al1 = (const float*)d_in[4];
  const float* ar1 = (const float*)d_in[5];
  const float* W2  = (const float*)d_in[6];
  const float* al2 = (const float*)d_in[7];
  const float* ar2 = (const float*)d_in[8];
  const float* W3  = (const float*)d_in[9];
  const float* al3 = (const float*)d_in[10];
  const float* ar3 = (const float*)d_in[11];

  const int N = in_sizes[0] / DIN;
  const int E = in_sizes[1];
  const int NB = (E + EPB - 1) / EPB;       // phase-1 blocks
  const int NHB = (N + 255) / 256;          // buckets covering all nodes

  auto alignup = [](size_t x){ return (x + 255) & ~(size_t)255; };
  char* p = (char*)d_ws;
  int* offsets = (int*)p; p += alignup(((size_t)N+1)*4);
  int* srcs    = (int*)p; p += alignup((size_t)E*4);
  int* ghist   = (int*)p; p += alignup((size_t)256*NB*4);
  int* btot    = (int*)p; p += alignup(257*4);
  uint2* ebuf  = (uint2*)p; p += alignup((size_t)E*8);
  unsigned short* Fb = (unsigned short*)p; p += alignup((size_t)N*DHID*2);
  float* X     = (float*)p; p += alignup((size_t)N*DHID*4);
  float* el    = (float*)p; p += alignup((size_t)N*4);
  float* er    = (float*)p; p += alignup((size_t)N*4);
  unsigned short* Wp1 = (unsigned short*)p; p += alignup((size_t)2*DIN*DHID*2);
  unsigned short* Wp2 = (unsigned short*)p; p += alignup((size_t)2*DHID*DHID*2);
  unsigned short* Wp3 = (unsigned short*)p; p += alignup((size_t)2*DHID*DOUTC*2);

  const int nbW4 = (N+3)/4;
  const int nbG  = (N+63)/64;

  pack_kernel<DIN ,DHID ><<<(DIN/32)*(DHID/16)*64/256,  256,0,stream>>>(W1, Wp1);
  pack_kernel<DHID,DHID ><<<(DHID/32)*(DHID/16)*64/256, 256,0,stream>>>(W2, Wp2);
  pack_kernel<DHID,DOUTC><<<(DHID/32)*(DOUTC/16)*64/256,256,0,stream>>>(W3, Wp3);

  // CSR build (atomic-free)
  rs_hist   <<<NB, 256,0,stream>>>(dst, ghist, E, NB);
  rs_scan   <<<256,256,0,stream>>>(ghist, btot, NB);
  rs_scan2  <<<1,  256,0,stream>>>(btot, offsets, N, E);
  rs_scatter<<<NB, 256,0,stream>>>(src, dst, ghist, btot, ebuf, E, NB);
  bucket_sort<<<NHB,256,0,stream>>>(ebuf, btot, offsets, srcs, N);

  // Layer 1: [N,256]@[256,128]
  gemm_mfma<DIN,DHID><<<nbG,256,0,stream>>>(h, Wp1, al1, ar1, Fb, el, er, N);
  agg3_kernel<128,true,false><<<nbW4,256,0,stream>>>(Fb, el, er, offsets, srcs, X, N);

  // Layer 2: [N,128]@[128,128]
  gemm_mfma<DHID,DHID><<<nbG,256,0,stream>>>(X, Wp2, al2, ar2, Fb, el, er, N);
  agg3_kernel<128,true,false><<<nbW4,256,0,stream>>>(Fb, el, er, offsets, srcs, X, N);

  // Layer 3: [N,128]@[128,64] + log_softmax
  gemm_mfma<DHID,DOUTC><<<nbG,256,0,stream>>>(X, Wp3, al3, ar3, Fb, el, er, N);
  agg3_kernel<64,false,true><<<nbW4,256,0,stream>>>(Fb, el, er, offsets, srcs, (float*)d_out, N);
}